// Round 2
// baseline (424.651 us; speedup 1.0000x reference)
//
#include <hip/hip_runtime.h>

// Fused GRU (Keras reset_after=True, relu) for MI355X — round 2.
// Block = 256 threads (4 waves), handles TWO batch rows. Grid = 256 = 1/CU.
//   Wave 0  : recurrence for both rows, wave-synchronous (no barriers inside
//             steps). Lane j owns unit j; computes rz,rr,rh dots for both rows
//             with packed float2 FMAs (k-pairs), U register-resident (192 VGPR,
//             shared by both rows). One LDS round-trip per step (h broadcast).
//   Waves 1-3: Phase-A producers: X[16][192] = inp_chunk @ W + b0 via bf16x3
//             MFMA, W frags register-resident (4 col-tiles per wave), double-
//             buffered into LDS. ONE __syncthreads per 16-step chunk.
// Epilogue (wave 0): h@W1 -> relu -> @W2 -> softmax for both rows.

#define B_SZ   512
#define T_SZ   512
#define F_SZ   128
#define UN     64
#define G3     192
#define CHUNK  16
#define NCHUNK (T_SZ / CHUNK)
#define NCLS   10
#define XPAD   193

using short8 = __attribute__((ext_vector_type(8))) short;
using f32x4  = __attribute__((ext_vector_type(4))) float;
using f32x2  = __attribute__((ext_vector_type(2))) float;

__device__ __forceinline__ unsigned short f2bf_rn(float f) {
    unsigned int u = __float_as_uint(f);
    unsigned int r = u + 0x7FFFu + ((u >> 16) & 1u);
    return (unsigned short)(r >> 16);
}
__device__ __forceinline__ float bf2f(unsigned short s) {
    return __uint_as_float(((unsigned int)s) << 16);
}
__device__ __forceinline__ float sigmoidf_(float x) {
    return 1.0f / (1.0f + __expf(-x));
}
__device__ __forceinline__ f32x2 fma2(f32x2 a, f32x2 b, f32x2 c) {
#if __has_builtin(__builtin_elementwise_fma)
    return __builtin_elementwise_fma(a, b, c);   // -> v_pk_fma_f32
#else
    f32x2 r; r.x = fmaf(a.x, b.x, c.x); r.y = fmaf(a.y, b.y, c.y); return r;
#endif
}
// Wave-synchronous LDS fence: LDS ops of one wave complete in order; the
// waitcnt + memory clobber stops compiler reordering across it.
#define WAVE_SYNC() asm volatile("s_waitcnt lgkmcnt(0)" ::: "memory")

__global__ __launch_bounds__(256, 1)
void gru_fused2(const float* __restrict__ inp,   // [512,512,128]
                const float* __restrict__ W,     // [128,192]
                const float* __restrict__ U,     // [64,192]
                const float* __restrict__ bias,  // [2,192]
                const float* __restrict__ W1,    // [64,64]
                const float* __restrict__ b1,    // [64]
                const float* __restrict__ W2,    // [64,10]
                const float* __restrict__ b2,    // [10]
                float* __restrict__ out)         // [512,10]
{
    const int tid  = threadIdx.x;
    const int wave = tid >> 6;
    const int lane = tid & 63;
    const int l15  = lane & 15;
    const int l4   = lane >> 4;
    const int r0   = blockIdx.x * 2;

    __shared__ __align__(16) float Xb[2][2][CHUNK][XPAD]; // [buf][row][t][192]
    __shared__ __align__(16) float hb[2][UN];
    __shared__ __align__(16) float sc[2][UN];
    __shared__ float lg[2][NCLS];

    // ---------------- per-wave persistent state ----------------
    // Phase-A waves (1..3): W fragments for col-tiles 4*(wave-1)..+3
    short8 wfh[4][4], wfl[4][4];
    float  b0c[4];
    // Rec wave (0): U columns as k-pairs, shared across both rows
    f32x2 uz[32], ur[32], uh[32];
    float brz = 0.f, brr = 0.f, brh = 0.f;
    float h0 = 0.f, h1 = 0.f;

    if (wave != 0) {
        const int pw = wave - 1;
        #pragma unroll
        for (int t = 0; t < 4; ++t) {
            const int col = 16 * (4 * pw + t) + l15;
            b0c[t] = bias[col];
            #pragma unroll
            for (int kt = 0; kt < 4; ++kt) {
                #pragma unroll
                for (int e = 0; e < 8; ++e) {
                    float w = W[(32 * kt + 8 * l4 + e) * G3 + col];
                    unsigned short h = f2bf_rn(w);
                    unsigned short l = f2bf_rn(w - bf2f(h));
                    wfh[t][kt][e] = (short)h;
                    wfl[t][kt][e] = (short)l;
                }
            }
        }
    } else {
        #pragma unroll
        for (int k2 = 0; k2 < 32; ++k2) {
            uz[k2] = (f32x2){U[(2 * k2) * G3 + lane],       U[(2 * k2 + 1) * G3 + lane]};
            ur[k2] = (f32x2){U[(2 * k2) * G3 + 64 + lane],  U[(2 * k2 + 1) * G3 + 64 + lane]};
            uh[k2] = (f32x2){U[(2 * k2) * G3 + 128 + lane], U[(2 * k2 + 1) * G3 + 128 + lane]};
        }
        brz = bias[G3 + lane];
        brr = bias[G3 + 64 + lane];
        brh = bias[G3 + 128 + lane];
        hb[0][lane] = 0.f;
        hb[1][lane] = 0.f;
        WAVE_SYNC();
    }

    // ---------------- prologue: stage chunk 0 ----------------
    if (wave != 0) {
        const int pw = wave - 1;
        #pragma unroll
        for (int r = 0; r < 2; ++r) {
            const float* ap = inp + (size_t)(r0 + r) * T_SZ * F_SZ + (size_t)l15 * F_SZ + 8 * l4;
            f32x4 acc[4];
            #pragma unroll
            for (int t = 0; t < 4; ++t) acc[t] = (f32x4){0.f, 0.f, 0.f, 0.f};
            #pragma unroll
            for (int kt = 0; kt < 4; ++kt) {
                f32x4 v0 = *(const f32x4*)(ap + 32 * kt);
                f32x4 v1 = *(const f32x4*)(ap + 32 * kt + 4);
                float av[8] = {v0[0], v0[1], v0[2], v0[3], v1[0], v1[1], v1[2], v1[3]};
                short8 ah, al;
                #pragma unroll
                for (int e = 0; e < 8; ++e) {
                    unsigned short h = f2bf_rn(av[e]);
                    unsigned short l = f2bf_rn(av[e] - bf2f(h));
                    ah[e] = (short)h; al[e] = (short)l;
                }
                #pragma unroll
                for (int t = 0; t < 4; ++t) {
                    acc[t] = __builtin_amdgcn_mfma_f32_16x16x32_bf16(ah, wfh[t][kt], acc[t], 0, 0, 0);
                    acc[t] = __builtin_amdgcn_mfma_f32_16x16x32_bf16(al, wfh[t][kt], acc[t], 0, 0, 0);
                    acc[t] = __builtin_amdgcn_mfma_f32_16x16x32_bf16(ah, wfl[t][kt], acc[t], 0, 0, 0);
                }
            }
            #pragma unroll
            for (int t = 0; t < 4; ++t) {
                const int col = 16 * (4 * pw + t) + l15;
                #pragma unroll
                for (int q = 0; q < 4; ++q)
                    Xb[0][r][4 * l4 + q][col] = acc[t][q] + b0c[t];
            }
        }
    }
    __syncthreads();

    // ---------------- main loop over chunks ----------------
    for (int c = 0; c < NCHUNK; ++c) {
        if (wave != 0) {
            // stage chunk c+1 into buf (c+1)&1
            if (c + 1 < NCHUNK) {
                const int pw = wave - 1;
                const int buf = (c + 1) & 1;
                #pragma unroll
                for (int r = 0; r < 2; ++r) {
                    const float* ap = inp + (size_t)(r0 + r) * T_SZ * F_SZ
                                    + (size_t)((c + 1) * CHUNK + l15) * F_SZ + 8 * l4;
                    f32x4 acc[4];
                    #pragma unroll
                    for (int t = 0; t < 4; ++t) acc[t] = (f32x4){0.f, 0.f, 0.f, 0.f};
                    #pragma unroll
                    for (int kt = 0; kt < 4; ++kt) {
                        f32x4 v0 = *(const f32x4*)(ap + 32 * kt);
                        f32x4 v1 = *(const f32x4*)(ap + 32 * kt + 4);
                        float av[8] = {v0[0], v0[1], v0[2], v0[3], v1[0], v1[1], v1[2], v1[3]};
                        short8 ah, al;
                        #pragma unroll
                        for (int e = 0; e < 8; ++e) {
                            unsigned short h = f2bf_rn(av[e]);
                            unsigned short l = f2bf_rn(av[e] - bf2f(h));
                            ah[e] = (short)h; al[e] = (short)l;
                        }
                        #pragma unroll
                        for (int t = 0; t < 4; ++t) {
                            acc[t] = __builtin_amdgcn_mfma_f32_16x16x32_bf16(ah, wfh[t][kt], acc[t], 0, 0, 0);
                            acc[t] = __builtin_amdgcn_mfma_f32_16x16x32_bf16(al, wfh[t][kt], acc[t], 0, 0, 0);
                            acc[t] = __builtin_amdgcn_mfma_f32_16x16x32_bf16(ah, wfl[t][kt], acc[t], 0, 0, 0);
                        }
                    }
                    #pragma unroll
                    for (int t = 0; t < 4; ++t) {
                        const int col = 16 * (4 * pw + t) + l15;
                        #pragma unroll
                        for (int q = 0; q < 4; ++q)
                            Xb[buf][r][4 * l4 + q][col] = acc[t][q] + b0c[t];
                    }
                }
            }
        } else {
            // ---- recurrence: 16 wave-synchronous steps on Xb[c&1] ----
            const int buf = c & 1;
            for (int s = 0; s < CHUNK; ++s) {
                const float xz0 = Xb[buf][0][s][lane];
                const float xr0 = Xb[buf][0][s][64 + lane];
                const float xh0 = Xb[buf][0][s][128 + lane];
                const float xz1 = Xb[buf][1][s][lane];
                const float xr1 = Xb[buf][1][s][64 + lane];
                const float xh1 = Xb[buf][1][s][128 + lane];

                f32x2 az0 = (f32x2){0.f, 0.f}, ar0 = az0, ah0 = az0;
                f32x2 az1 = az0, ar1 = az0, ah1 = az0;
                #pragma unroll
                for (int kb = 0; kb < 8; ++kb) {
                    f32x4 h0a = *(const f32x4*)&hb[0][8 * kb];
                    f32x4 h0b = *(const f32x4*)&hb[0][8 * kb + 4];
                    f32x4 h1a = *(const f32x4*)&hb[1][8 * kb];
                    f32x4 h1b = *(const f32x4*)&hb[1][8 * kb + 4];
                    f32x2 p0[4] = {(f32x2){h0a[0], h0a[1]}, (f32x2){h0a[2], h0a[3]},
                                   (f32x2){h0b[0], h0b[1]}, (f32x2){h0b[2], h0b[3]}};
                    f32x2 p1[4] = {(f32x2){h1a[0], h1a[1]}, (f32x2){h1a[2], h1a[3]},
                                   (f32x2){h1b[0], h1b[1]}, (f32x2){h1b[2], h1b[3]}};
                    #pragma unroll
                    for (int p = 0; p < 4; ++p) {
                        const int k2 = 4 * kb + p;
                        az0 = fma2(p0[p], uz[k2], az0);
                        ar0 = fma2(p0[p], ur[k2], ar0);
                        ah0 = fma2(p0[p], uh[k2], ah0);
                        az1 = fma2(p1[p], uz[k2], az1);
                        ar1 = fma2(p1[p], ur[k2], ar1);
                        ah1 = fma2(p1[p], uh[k2], ah1);
                    }
                }
                {
                    float rz = az0[0] + az0[1] + brz;
                    float rr = ar0[0] + ar0[1] + brr;
                    float rh = ah0[0] + ah0[1] + brh;
                    float z  = sigmoidf_(xz0 + rz);
                    float rg = sigmoidf_(xr0 + rr);
                    float hh = fmaxf(fmaf(rg, rh, xh0), 0.f);
                    h0 = fmaf(z, h0 - hh, hh);
                }
                {
                    float rz = az1[0] + az1[1] + brz;
                    float rr = ar1[0] + ar1[1] + brr;
                    float rh = ah1[0] + ah1[1] + brh;
                    float z  = sigmoidf_(xz1 + rz);
                    float rg = sigmoidf_(xr1 + rr);
                    float hh = fmaxf(fmaf(rg, rh, xh1), 0.f);
                    h1 = fmaf(z, h1 - hh, hh);
                }
                hb[0][lane] = h0;
                hb[1][lane] = h1;
                WAVE_SYNC();
            }
        }
        __syncthreads();
    }

    // ---------------- epilogue: heads for both rows (wave 0) ----------------
    if (wave == 0) {
        float a0 = b1[lane], a1 = b1[lane];
        #pragma unroll 8
        for (int k = 0; k < UN; ++k) {
            float w  = W1[k * UN + lane];
            a0 = fmaf(hb[0][k], w, a0);
            a1 = fmaf(hb[1][k], w, a1);
        }
        sc[0][lane] = fmaxf(a0, 0.f);
        sc[1][lane] = fmaxf(a1, 0.f);
        WAVE_SYNC();

        const int g = lane >> 4;       // 0 -> row0, 1 -> row1
        const int j = lane & 15;
        if (g < 2 && j < NCLS) {
            float a = b2[j];
            #pragma unroll 8
            for (int k = 0; k < UN; ++k)
                a = fmaf(sc[g][k], W2[k * NCLS + j], a);
            lg[g][j] = a;
        }
        WAVE_SYNC();
        if (g < 2 && j < NCLS) {
            float m = lg[g][0];
            #pragma unroll
            for (int k = 1; k < NCLS; ++k) m = fmaxf(m, lg[g][k]);
            float ssum = 0.f;
            #pragma unroll
            for (int k = 0; k < NCLS; ++k) ssum += __expf(lg[g][k] - m);
            out[(r0 + g) * NCLS + j] = __expf(lg[g][j] - m) / ssum;
        }
    }
}

extern "C" void kernel_launch(void* const* d_in, const int* in_sizes, int n_in,
                              void* d_out, int out_size, void* d_ws, size_t ws_size,
                              hipStream_t stream) {
    const float* inp  = (const float*)d_in[0];
    const float* W    = (const float*)d_in[1];
    const float* U    = (const float*)d_in[2];
    const float* bias = (const float*)d_in[3];
    const float* W1   = (const float*)d_in[4];
    const float* b1   = (const float*)d_in[5];
    const float* W2   = (const float*)d_in[6];
    const float* b2   = (const float*)d_in[7];
    float* out = (float*)d_out;

    gru_fused2<<<B_SZ / 2, 256, 0, stream>>>(inp, W, U, bias, W1, b1, W2, b2, out);
}